// Round 10
// baseline (168.849 us; speedup 1.0000x reference)
//
#include <hip/hip_runtime.h>

#define N_ROWS 131072
#define DIM 64
#define KCODES 512
#define MARGIN 1e-4f

typedef __attribute__((ext_vector_type(8))) short bf16x8;
typedef __attribute__((ext_vector_type(4))) float f32x4;

// ws layout (4-byte words):
// [0]            loss_sum f32 (atomic, zeroed per launch)
// [1..4)         pad
// [4..4100)      hist8 u32[8][512] striped count partials (zeroed per launch)
// [4100..4612)   bnp f32[512]
// [4612..37380)  wfrag ushort[65536] B-fragment image:
//                frag = cti*256 + q*64 + lane (16B units); q: 0=hi k0,1=hi k1,2=lo k0,3=lo k1

__device__ __forceinline__ float sqr_nf(float x) {
    float s = x * x;
    asm("" : "+v"(s));   // numpy rounds the square before summing
    return s;
}

__device__ __forceinline__ unsigned short f2bf(float f) {  // RNE, finite data
    unsigned u = __float_as_uint(f);
    u += 0x7fffu + ((u >> 16) & 1u);
    return (unsigned short)(u >> 16);
}
__device__ __forceinline__ float bf2f(unsigned short b) {
    return __uint_as_float(((unsigned)b) << 16);
}

__device__ __forceinline__ void cvtpair(float4 a, float4 b, bf16x8& hi, bf16x8& lo) {
    float v[8] = {a.x, a.y, a.z, a.w, b.x, b.y, b.z, b.w};
#pragma unroll
    for (int j = 0; j < 8; ++j) {
        unsigned short h = f2bf(v[j]);
        hi[j] = (short)h;
        lo[j] = (short)f2bf(v[j] - bf2f(h));
    }
}
__device__ __forceinline__ float4 scl(float4 v, float s) {
    return make_float4(v.x * s, v.y * s, v.z * s, v.w * s);
}

// ---- precompute: W -> bf16 hi/lo B-fragment image + np-exact norms ---------
__global__ __launch_bounds__(256) void vq_wprep_k(
    const float* __restrict__ W, unsigned short* __restrict__ wfrag,
    float* __restrict__ bnp) {
    int code = blockIdx.x * 256 + threadIdx.x;   // 0..511
    float p[64];
#pragma unroll
    for (int i = 0; i < 16; ++i) {
        float4 v = reinterpret_cast<const float4*>(W)[code * 16 + i];
        p[i * 4 + 0] = v.x; p[i * 4 + 1] = v.y;
        p[i * 4 + 2] = v.z; p[i * 4 + 3] = v.w;
    }
    unsigned short hi[64], lo[64];
#pragma unroll
    for (int d = 0; d < 64; ++d) {
        hi[d] = f2bf(p[d]);
        lo[d] = f2bf(p[d] - bf2f(hi[d]));
    }
    {   // np pairwise codeword norm  [validated rounds 3-8, absmax 0]
        float r[8];
#pragma unroll
        for (int j = 0; j < 8; ++j) r[j] = sqr_nf(p[j]);
#pragma unroll
        for (int i = 1; i < 8; ++i)
#pragma unroll
            for (int j = 0; j < 8; ++j) r[j] += sqr_nf(p[i * 8 + j]);
        bnp[code] = ((r[0] + r[1]) + (r[2] + r[3])) + ((r[4] + r[5]) + (r[6] + r[7]));
    }
    const int cti = code >> 4, m = code & 15;
#pragma unroll
    for (int part = 0; part < 2; ++part) {
        const unsigned short* src = part ? lo : hi;
#pragma unroll
        for (int s = 0; s < 2; ++s) {
            int q = part * 2 + s;
#pragma unroll
            for (int kq = 0; kq < 4; ++kq) {
                int lane = kq * 16 + m;
                size_t off = ((size_t)(cti * 4 + q) * 64 + lane) * 8;
                *reinterpret_cast<uint4*>(wfrag + off) =
                    *reinterpret_cast<const uint4*>(src + s * 32 + kq * 8);
            }
        }
    }
}

// ---- K1: PURE scoring. No LDS, no barriers, 4 independent waves/block ------
__global__ __launch_bounds__(256, 4) void vq_score_k(
    const float* __restrict__ X, const unsigned short* __restrict__ wfrag,
    const float* __restrict__ bnp, float* __restrict__ out_idx) {
    const int tid = threadIdx.x;
    const int lane = tid & 63, w = tid >> 6;
    const int m = lane & 15, kq = lane >> 4;
    const long rbase = (long)blockIdx.x * 128;

    // A-fragments hold -2x (exact scale): lane (m,kq) holds A[m][kq*8+j]
    bf16x8 ahi[2][2], alo[2][2];
#pragma unroll
    for (int rt = 0; rt < 2; ++rt) {
        long row = rbase + w * 32 + rt * 16 + m;
        const float4* xp = reinterpret_cast<const float4*>(X + row * DIM);
        cvtpair(scl(xp[kq * 2], -2.f), scl(xp[kq * 2 + 1], -2.f),
                ahi[rt][0], alo[rt][0]);
        cvtpair(scl(xp[8 + kq * 2], -2.f), scl(xp[8 + kq * 2 + 1], -2.f),
                ahi[rt][1], alo[rt][1]);
    }

    float best[2][4], sec[2][4];
    int bidx[2][4];
#pragma unroll
    for (int rt = 0; rt < 2; ++rt)
#pragma unroll
        for (int j = 0; j < 4; ++j) { best[rt][j] = 3e38f; sec[rt][j] = 3e38f; bidx[rt][j] = 0; }

    const bf16x8* fb = reinterpret_cast<const bf16x8*>(wfrag);
    bf16x8 nb0 = fb[lane], nb1 = fb[64 + lane], nb2 = fb[128 + lane], nb3 = fb[192 + lane];
    for (int cti = 0; cti < 32; ++cti) {
        bf16x8 b0 = nb0, b1 = nb1, b2 = nb2, b3 = nb3;
        if (cti < 31) {
            int nbase = (cti + 1) * 256;
            nb0 = fb[nbase + lane];       nb1 = fb[nbase + 64 + lane];
            nb2 = fb[nbase + 128 + lane]; nb3 = fb[nbase + 192 + lane];
        }
        const int kk = cti * 16 + m;
        const float wn = bnp[kk];
        // score = wn + sum((-2x) * w): hh(k0,k1) + lh(k0,k1) + hl(k0,k1)
        f32x4 c0 = {wn, wn, wn, wn};
        f32x4 c1 = {wn, wn, wn, wn};
        c0 = __builtin_amdgcn_mfma_f32_16x16x32_bf16(ahi[0][0], b0, c0, 0, 0, 0);
        c1 = __builtin_amdgcn_mfma_f32_16x16x32_bf16(ahi[1][0], b0, c1, 0, 0, 0);
        c0 = __builtin_amdgcn_mfma_f32_16x16x32_bf16(ahi[0][1], b1, c0, 0, 0, 0);
        c1 = __builtin_amdgcn_mfma_f32_16x16x32_bf16(ahi[1][1], b1, c1, 0, 0, 0);
        c0 = __builtin_amdgcn_mfma_f32_16x16x32_bf16(alo[0][0], b0, c0, 0, 0, 0);
        c1 = __builtin_amdgcn_mfma_f32_16x16x32_bf16(alo[1][0], b0, c1, 0, 0, 0);
        c0 = __builtin_amdgcn_mfma_f32_16x16x32_bf16(alo[0][1], b1, c0, 0, 0, 0);
        c1 = __builtin_amdgcn_mfma_f32_16x16x32_bf16(alo[1][1], b1, c1, 0, 0, 0);
        c0 = __builtin_amdgcn_mfma_f32_16x16x32_bf16(ahi[0][0], b2, c0, 0, 0, 0);
        c1 = __builtin_amdgcn_mfma_f32_16x16x32_bf16(ahi[1][0], b2, c1, 0, 0, 0);
        c0 = __builtin_amdgcn_mfma_f32_16x16x32_bf16(ahi[0][1], b3, c0, 0, 0, 0);
        c1 = __builtin_amdgcn_mfma_f32_16x16x32_bf16(ahi[1][1], b3, c1, 0, 0, 0);
#pragma unroll
        for (int rt = 0; rt < 2; ++rt)
#pragma unroll
            for (int j = 0; j < 4; ++j) {
                float s = (rt == 0) ? c0[j] : c1[j];
                float nb = fminf(best[rt][j], s);
                float ns = fminf(sec[rt][j], fmaxf(best[rt][j], s));
                bidx[rt][j] = (s < best[rt][j]) ? kk : bidx[rt][j];
                best[rt][j] = nb; sec[rt][j] = ns;
            }
    }

    // merge across the 16 m-lanes; exact ties -> smaller index
#pragma unroll
    for (int st = 1; st < 16; st <<= 1) {
#pragma unroll
        for (int rt = 0; rt < 2; ++rt)
#pragma unroll
            for (int j = 0; j < 4; ++j) {
                float ob = __shfl_xor(best[rt][j], st);
                float os = __shfl_xor(sec[rt][j], st);
                int oi = __shfl_xor(bidx[rt][j], st);
                if (ob < best[rt][j] || (ob == best[rt][j] && oi < bidx[rt][j])) {
                    sec[rt][j] = fminf(best[rt][j], os);
                    best[rt][j] = ob; bidx[rt][j] = oi;
                } else {
                    sec[rt][j] = fminf(sec[rt][j], ob);
                }
            }
    }

    if (m == 0) {   // C/D row = kq*4 + j
#pragma unroll
        for (int rt = 0; rt < 2; ++rt)
#pragma unroll
            for (int j = 0; j < 4; ++j) {
                int r = w * 32 + rt * 16 + kq * 4 + j;
                int id = (sec[rt][j] - best[rt][j] <= MARGIN) ? -1 : bidx[rt][j];
                out_idx[rbase + r] = (float)id;
            }
    }
}

// ---- K2: epilogue + np-exact refine + hist + loss --------------------------
__global__ __launch_bounds__(256) void vq_post_k(
    const float* __restrict__ X, const float* __restrict__ Wf,
    const float* __restrict__ bnp,
    float* __restrict__ out_q, float* __restrict__ out_idx,
    unsigned* __restrict__ hist8, float* __restrict__ loss_sum) {
    __shared__ unsigned hist[KCODES];
    __shared__ float lred[4];
    const int tid = threadIdx.x;
    const int lane = tid & 63, w = tid >> 6;
    const long base = (long)blockIdx.x * 64;

    for (int i = tid; i < KCODES; i += 256) hist[i] = 0;   // FIX: full range
    __syncthreads();

    float ls = 0.f;
    for (int i = 0; i < 16; ++i) {
        const long row = base + w * 16 + i;
        const float idf = out_idx[row];            // uniform across wave
        const float xv = X[row * DIM + lane];      // lane d holds x[d]
        int k;
        if (idf >= 0.f) {
            k = (int)idf;
        } else {
            // np-bit-exact resolve [validated rounds 3-8]
            float sq = sqr_nf(xv);
            float rr = sq;
#pragma unroll
            for (int t = 1; t < 8; ++t) rr += __shfl(sq, (lane & 7) + 8 * t);
            float t01 = rr + __shfl_xor(rr, 1);
            float t03 = t01 + __shfl_xor(t01, 2);
            float Afull = t03 + __shfl_xor(t03, 4);
            const float A = __shfl(Afull, 0);
            float acc[8];
#pragma unroll
            for (int c = 0; c < 8; ++c) acc[c] = 0.f;
            for (int d0 = 0; d0 < 16; ++d0) {
                float x0 = __shfl(xv, d0 * 4 + 0);
                float x1 = __shfl(xv, d0 * 4 + 1);
                float x2 = __shfl(xv, d0 * 4 + 2);
                float x3 = __shfl(xv, d0 * 4 + 3);
#pragma unroll
                for (int c = 0; c < 8; ++c) {
                    float4 wq = *reinterpret_cast<const float4*>(
                        &Wf[(lane * 8 + c) * DIM + d0 * 4]);
                    acc[c] = fmaf(x0, wq.x, acc[c]);
                    acc[c] = fmaf(x1, wq.y, acc[c]);
                    acc[c] = fmaf(x2, wq.z, acc[c]);
                    acc[c] = fmaf(x3, wq.w, acc[c]);
                }
            }
            float bs = 3e38f;
            int bi = 0;
#pragma unroll
            for (int c = 0; c < 8; ++c) {
                int kk = lane * 8 + c;
                float u = A + bnp[kk];
                float s = u - 2.0f * acc[c];
                if (s < bs) { bs = s; bi = kk; }   // ascending k, strict <
            }
#pragma unroll
            for (int st = 1; st < 64; st <<= 1) {
                float ob = __shfl_xor(bs, st);
                int oi = __shfl_xor(bi, st);
                if (ob < bs || (ob == bs && oi < bi)) { bs = ob; bi = oi; }
            }
            k = bi;
            if (lane == 0) out_idx[row] = (float)k;
        }
        if (lane == 0) atomicAdd(&hist[k], 1u);
        float qv = Wf[k * DIM + lane];
        float diff = qv - xv;
        out_q[row * DIM + lane] = xv + diff;       // inputs + (quantized - inputs)
        ls = fmaf(diff, diff, ls);
    }

#pragma unroll
    for (int st = 1; st < 64; st <<= 1) ls += __shfl_xor(ls, st);
    if (lane == 0) lred[w] = ls;
    __syncthreads();
    if (tid == 0) atomicAdd(loss_sum, lred[0] + lred[1] + lred[2] + lred[3]);
    for (int i = tid; i < KCODES; i += 256) {      // FIX: full range
        unsigned v = hist[i];
        if (v) atomicAdd(&hist8[(blockIdx.x & 7) * KCODES + i], v);
    }
}

__global__ __launch_bounds__(512) void vq_finalize_k(
    const unsigned* __restrict__ hist8, const float* __restrict__ loss_sum,
    float* __restrict__ out_loss, float* __restrict__ out_perp) {
    __shared__ float red[512];
    int t = threadIdx.x;
    unsigned c = 0;
#pragma unroll
    for (int s = 0; s < 8; ++s) c += hist8[s * KCODES + t];
    float p = (float)c * (1.0f / (float)N_ROWS);
    red[t] = p * logf(p + 1e-10f);
    __syncthreads();
    for (int off = 256; off; off >>= 1) {
        if (t < off) red[t] += red[t + off];
        __syncthreads();
    }
    if (t == 0) {
        *out_perp = expf(-red[0]);
        float m = *loss_sum / (float)(N_ROWS * DIM);
        *out_loss = m + 0.25f * m;
    }
}

extern "C" void kernel_launch(void* const* d_in, const int* in_sizes, int n_in,
                              void* d_out, int out_size, void* d_ws, size_t ws_size,
                              hipStream_t stream) {
    const float* X = (const float*)d_in[0];
    const float* Wf = (const float*)d_in[1];

    float* out = (float*)d_out;
    float* out_loss = out;
    float* out_q = out + 1;
    float* out_perp = out + 1 + (long)N_ROWS * DIM;
    float* out_idx = out + 2 + (long)N_ROWS * DIM;

    unsigned* wsu = (unsigned*)d_ws;
    float* loss_sum = (float*)d_ws;                 // [0]
    unsigned* hist8 = wsu + 4;                      // [4..4100)
    float* bnp = (float*)(wsu + 4100);              // [4100..4612)
    unsigned short* wfrag = (unsigned short*)(wsu + 4612);  // [4612..37380)

    hipMemsetAsync(d_ws, 0, 16400, stream);         // loss + hist8
    vq_wprep_k<<<2, 256, 0, stream>>>(Wf, wfrag, bnp);
    vq_score_k<<<N_ROWS / 128, 256, 0, stream>>>(X, wfrag, bnp, out_idx);
    vq_post_k<<<N_ROWS / 64, 256, 0, stream>>>(X, Wf, bnp, out_q, out_idx,
                                               hist8, loss_sum);
    vq_finalize_k<<<1, 512, 0, stream>>>(hist8, loss_sum, out_loss, out_perp);
}

// Round 11
// 137.106 us; speedup vs baseline: 1.2315x; 1.2315x over previous
//
#include <hip/hip_runtime.h>

#define N_ROWS 131072
#define DIM 64
#define KCODES 512
#define MARGIN 1e-4f

typedef __attribute__((ext_vector_type(8))) short bf16x8;
typedef __attribute__((ext_vector_type(4))) float f32x4;

// ws layout (4-byte words):
// [0..256)       lossp f32[256]  striped loss partials (zeroed)
// [256..4352)    hist8 u32[8][512] striped count partials (zeroed)
// [4352..4864)   bnp f32[512]
// [4864..37632)  wfrag ushort[65536] B-fragment image:
//                frag = cti*256 + q*64 + lane (16B units); q: 0=hi k0,1=hi k1,2=lo k0,3=lo k1

__device__ __forceinline__ float sqr_nf(float x) {
    float s = x * x;
    asm("" : "+v"(s));   // numpy rounds the square before summing
    return s;
}

__device__ __forceinline__ unsigned short f2bf(float f) {  // RNE, finite data
    unsigned u = __float_as_uint(f);
    u += 0x7fffu + ((u >> 16) & 1u);
    return (unsigned short)(u >> 16);
}
__device__ __forceinline__ float bf2f(unsigned short b) {
    return __uint_as_float(((unsigned)b) << 16);
}

__device__ __forceinline__ void cvtpair(float4 a, float4 b, bf16x8& hi, bf16x8& lo) {
    float v[8] = {a.x, a.y, a.z, a.w, b.x, b.y, b.z, b.w};
#pragma unroll
    for (int j = 0; j < 8; ++j) {
        unsigned short h = f2bf(v[j]);
        hi[j] = (short)h;
        lo[j] = (short)f2bf(v[j] - bf2f(h));
    }
}
__device__ __forceinline__ float4 scl(float4 v, float s) {
    return make_float4(v.x * s, v.y * s, v.z * s, v.w * s);
}

// ---- precompute: W -> bf16 hi/lo B-fragment image + np-exact norms ---------
__global__ __launch_bounds__(256) void vq_wprep_k(
    const float* __restrict__ W, unsigned short* __restrict__ wfrag,
    float* __restrict__ bnp) {
    int code = blockIdx.x * 256 + threadIdx.x;   // 0..511
    float p[64];
#pragma unroll
    for (int i = 0; i < 16; ++i) {
        float4 v = reinterpret_cast<const float4*>(W)[code * 16 + i];
        p[i * 4 + 0] = v.x; p[i * 4 + 1] = v.y;
        p[i * 4 + 2] = v.z; p[i * 4 + 3] = v.w;
    }
    unsigned short hi[64], lo[64];
#pragma unroll
    for (int d = 0; d < 64; ++d) {
        hi[d] = f2bf(p[d]);
        lo[d] = f2bf(p[d] - bf2f(hi[d]));
    }
    {   // np pairwise codeword norm  [validated rounds 3-10, absmax 0]
        float r[8];
#pragma unroll
        for (int j = 0; j < 8; ++j) r[j] = sqr_nf(p[j]);
#pragma unroll
        for (int i = 1; i < 8; ++i)
#pragma unroll
            for (int j = 0; j < 8; ++j) r[j] += sqr_nf(p[i * 8 + j]);
        bnp[code] = ((r[0] + r[1]) + (r[2] + r[3])) + ((r[4] + r[5]) + (r[6] + r[7]));
    }
    const int cti = code >> 4, m = code & 15;
#pragma unroll
    for (int part = 0; part < 2; ++part) {
        const unsigned short* src = part ? lo : hi;
#pragma unroll
        for (int s = 0; s < 2; ++s) {
            int q = part * 2 + s;
#pragma unroll
            for (int kq = 0; kq < 4; ++kq) {
                int lane = kq * 16 + m;
                size_t off = ((size_t)(cti * 4 + q) * 64 + lane) * 8;
                *reinterpret_cast<uint4*>(wfrag + off) =
                    *reinterpret_cast<const uint4*>(src + s * 32 + kq * 8);
            }
        }
    }
}

// ---- K1: PURE scoring. No LDS, no barriers (unchanged, ~30us) --------------
__global__ __launch_bounds__(256, 4) void vq_score_k(
    const float* __restrict__ X, const unsigned short* __restrict__ wfrag,
    const float* __restrict__ bnp, float* __restrict__ out_idx) {
    const int tid = threadIdx.x;
    const int lane = tid & 63, w = tid >> 6;
    const int m = lane & 15, kq = lane >> 4;
    const long rbase = (long)blockIdx.x * 128;

    bf16x8 ahi[2][2], alo[2][2];
#pragma unroll
    for (int rt = 0; rt < 2; ++rt) {
        long row = rbase + w * 32 + rt * 16 + m;
        const float4* xp = reinterpret_cast<const float4*>(X + row * DIM);
        cvtpair(scl(xp[kq * 2], -2.f), scl(xp[kq * 2 + 1], -2.f),
                ahi[rt][0], alo[rt][0]);
        cvtpair(scl(xp[8 + kq * 2], -2.f), scl(xp[8 + kq * 2 + 1], -2.f),
                ahi[rt][1], alo[rt][1]);
    }

    float best[2][4], sec[2][4];
    int bidx[2][4];
#pragma unroll
    for (int rt = 0; rt < 2; ++rt)
#pragma unroll
        for (int j = 0; j < 4; ++j) { best[rt][j] = 3e38f; sec[rt][j] = 3e38f; bidx[rt][j] = 0; }

    const bf16x8* fb = reinterpret_cast<const bf16x8*>(wfrag);
    bf16x8 nb0 = fb[lane], nb1 = fb[64 + lane], nb2 = fb[128 + lane], nb3 = fb[192 + lane];
    for (int cti = 0; cti < 32; ++cti) {
        bf16x8 b0 = nb0, b1 = nb1, b2 = nb2, b3 = nb3;
        if (cti < 31) {
            int nbase = (cti + 1) * 256;
            nb0 = fb[nbase + lane];       nb1 = fb[nbase + 64 + lane];
            nb2 = fb[nbase + 128 + lane]; nb3 = fb[nbase + 192 + lane];
        }
        const int kk = cti * 16 + m;
        const float wn = bnp[kk];
        f32x4 c0 = {wn, wn, wn, wn};
        f32x4 c1 = {wn, wn, wn, wn};
        c0 = __builtin_amdgcn_mfma_f32_16x16x32_bf16(ahi[0][0], b0, c0, 0, 0, 0);
        c1 = __builtin_amdgcn_mfma_f32_16x16x32_bf16(ahi[1][0], b0, c1, 0, 0, 0);
        c0 = __builtin_amdgcn_mfma_f32_16x16x32_bf16(ahi[0][1], b1, c0, 0, 0, 0);
        c1 = __builtin_amdgcn_mfma_f32_16x16x32_bf16(ahi[1][1], b1, c1, 0, 0, 0);
        c0 = __builtin_amdgcn_mfma_f32_16x16x32_bf16(alo[0][0], b0, c0, 0, 0, 0);
        c1 = __builtin_amdgcn_mfma_f32_16x16x32_bf16(alo[1][0], b0, c1, 0, 0, 0);
        c0 = __builtin_amdgcn_mfma_f32_16x16x32_bf16(alo[0][1], b1, c0, 0, 0, 0);
        c1 = __builtin_amdgcn_mfma_f32_16x16x32_bf16(alo[1][1], b1, c1, 0, 0, 0);
        c0 = __builtin_amdgcn_mfma_f32_16x16x32_bf16(ahi[0][0], b2, c0, 0, 0, 0);
        c1 = __builtin_amdgcn_mfma_f32_16x16x32_bf16(ahi[1][0], b2, c1, 0, 0, 0);
        c0 = __builtin_amdgcn_mfma_f32_16x16x32_bf16(ahi[0][1], b3, c0, 0, 0, 0);
        c1 = __builtin_amdgcn_mfma_f32_16x16x32_bf16(ahi[1][1], b3, c1, 0, 0, 0);
#pragma unroll
        for (int rt = 0; rt < 2; ++rt)
#pragma unroll
            for (int j = 0; j < 4; ++j) {
                float s = (rt == 0) ? c0[j] : c1[j];
                float nb = fminf(best[rt][j], s);
                float ns = fminf(sec[rt][j], fmaxf(best[rt][j], s));
                bidx[rt][j] = (s < best[rt][j]) ? kk : bidx[rt][j];
                best[rt][j] = nb; sec[rt][j] = ns;
            }
    }

#pragma unroll
    for (int st = 1; st < 16; st <<= 1) {
#pragma unroll
        for (int rt = 0; rt < 2; ++rt)
#pragma unroll
            for (int j = 0; j < 4; ++j) {
                float ob = __shfl_xor(best[rt][j], st);
                float os = __shfl_xor(sec[rt][j], st);
                int oi = __shfl_xor(bidx[rt][j], st);
                if (ob < best[rt][j] || (ob == best[rt][j] && oi < bidx[rt][j])) {
                    sec[rt][j] = fminf(best[rt][j], os);
                    best[rt][j] = ob; bidx[rt][j] = oi;
                } else {
                    sec[rt][j] = fminf(sec[rt][j], ob);
                }
            }
    }

    if (m == 0) {   // C/D row = kq*4 + j
#pragma unroll
        for (int rt = 0; rt < 2; ++rt)
#pragma unroll
            for (int j = 0; j < 4; ++j) {
                int r = w * 32 + rt * 16 + kq * 4 + j;
                int id = (sec[rt][j] - best[rt][j] <= MARGIN) ? -1 : bidx[rt][j];
                out_idx[rbase + r] = (float)id;
            }
    }
}

// ---- K2 v2: wide epilogue. Wave = 4 rows, float4/lane, no serial chains ----
__global__ __launch_bounds__(256) void vq_post_k(
    const float* __restrict__ X, const float* __restrict__ Wf,
    const float* __restrict__ bnp,
    float* __restrict__ out_q, float* __restrict__ out_idx,
    unsigned* __restrict__ hist8, float* __restrict__ lossp) {
    const int tid = threadIdx.x;
    const int lane = tid & 63, w = tid >> 6;
    const int sub = lane >> 4, l16 = lane & 15;
    const long rowg = (long)blockIdx.x * 16 + w * 4;   // wave's first row
    const unsigned hstripe = (blockIdx.x & 7) * KCODES;

    float ls = 0.f;
    const long row = rowg + sub;
    const float idf = out_idx[row];
    if (idf >= 0.f) {
        const int k = (int)idf;
        float4 x4 = reinterpret_cast<const float4*>(X)[row * 16 + l16];
        float4 w4 = reinterpret_cast<const float4*>(Wf)[(long)k * 16 + l16];
        float4 o; float t;
        t = w4.x - x4.x; o.x = x4.x + t; ls = fmaf(t, t, ls);
        t = w4.y - x4.y; o.y = x4.y + t; ls = fmaf(t, t, ls);
        t = w4.z - x4.z; o.z = x4.z + t; ls = fmaf(t, t, ls);
        t = w4.w - x4.w; o.w = x4.w + t; ls = fmaf(t, t, ls);
        reinterpret_cast<float4*>(out_q)[row * 16 + l16] = o;
        if (l16 == 0) atomicAdd(&hist8[hstripe + k], 1u);
    }

    // flagged rows (~1.7%): full-wave np-bit-exact resolve [validated r3-r10]
    unsigned long long mask = __ballot(idf < 0.f);
    if (mask) {
#pragma unroll
        for (int s = 0; s < 4; ++s) {
            if (!(mask & (1ull << (s * 16)))) continue;
            const long rrow = rowg + s;
            const float xv = X[rrow * DIM + lane];   // lane d holds x[d]
            float sq = sqr_nf(xv);
            float rr = sq;
#pragma unroll
            for (int t2 = 1; t2 < 8; ++t2) rr += __shfl(sq, (lane & 7) + 8 * t2);
            float t01 = rr + __shfl_xor(rr, 1);
            float t03 = t01 + __shfl_xor(t01, 2);
            float Afull = t03 + __shfl_xor(t03, 4);
            const float A = __shfl(Afull, 0);
            float acc[8];
#pragma unroll
            for (int c = 0; c < 8; ++c) acc[c] = 0.f;
            for (int d0 = 0; d0 < 16; ++d0) {
                float x0 = __shfl(xv, d0 * 4 + 0);
                float x1 = __shfl(xv, d0 * 4 + 1);
                float x2 = __shfl(xv, d0 * 4 + 2);
                float x3 = __shfl(xv, d0 * 4 + 3);
#pragma unroll
                for (int c = 0; c < 8; ++c) {
                    float4 wq = *reinterpret_cast<const float4*>(
                        &Wf[(lane * 8 + c) * DIM + d0 * 4]);
                    acc[c] = fmaf(x0, wq.x, acc[c]);
                    acc[c] = fmaf(x1, wq.y, acc[c]);
                    acc[c] = fmaf(x2, wq.z, acc[c]);
                    acc[c] = fmaf(x3, wq.w, acc[c]);
                }
            }
            float bs = 3e38f;
            int bi = 0;
#pragma unroll
            for (int c = 0; c < 8; ++c) {
                int kk = lane * 8 + c;
                float u = A + bnp[kk];
                float s2 = u - 2.0f * acc[c];
                if (s2 < bs) { bs = s2; bi = kk; }   // ascending k, strict <
            }
#pragma unroll
            for (int st = 1; st < 64; st <<= 1) {
                float ob = __shfl_xor(bs, st);
                int oi = __shfl_xor(bi, st);
                if (ob < bs || (ob == bs && oi < bi)) { bs = ob; bi = oi; }
            }
            const int k = bi;
            if (lane == 0) {
                out_idx[rrow] = (float)k;
                atomicAdd(&hist8[hstripe + k], 1u);
            }
            float qv = Wf[k * DIM + lane];
            float diff = qv - xv;
            out_q[rrow * DIM + lane] = xv + diff;
            ls = fmaf(diff, diff, ls);
        }
    }

#pragma unroll
    for (int st = 1; st < 64; st <<= 1) ls += __shfl_xor(ls, st);
    if (lane == 0 && ls != 0.f) atomicAdd(&lossp[blockIdx.x & 255], ls);
}

__global__ __launch_bounds__(512) void vq_finalize_k(
    const unsigned* __restrict__ hist8, const float* __restrict__ lossp,
    float* __restrict__ out_loss, float* __restrict__ out_perp) {
    __shared__ float red[512];
    int t = threadIdx.x;
    unsigned c = 0;
#pragma unroll
    for (int s = 0; s < 8; ++s) c += hist8[s * KCODES + t];
    float p = (float)c * (1.0f / (float)N_ROWS);
    red[t] = p * logf(p + 1e-10f);
    __syncthreads();
    for (int off = 256; off; off >>= 1) {
        if (t < off) red[t] += red[t + off];
        __syncthreads();
    }
    if (t == 0) *out_perp = expf(-red[0]);
    __syncthreads();
    red[t] = (t < 256) ? lossp[t] : 0.f;
    __syncthreads();
    for (int off = 256; off; off >>= 1) {
        if (t < off) red[t] += red[t + off];
        __syncthreads();
    }
    if (t == 0) {
        float m = red[0] / (float)(N_ROWS * DIM);
        *out_loss = m + 0.25f * m;
    }
}

extern "C" void kernel_launch(void* const* d_in, const int* in_sizes, int n_in,
                              void* d_out, int out_size, void* d_ws, size_t ws_size,
                              hipStream_t stream) {
    const float* X = (const float*)d_in[0];
    const float* Wf = (const float*)d_in[1];

    float* out = (float*)d_out;
    float* out_loss = out;
    float* out_q = out + 1;
    float* out_perp = out + 1 + (long)N_ROWS * DIM;
    float* out_idx = out + 2 + (long)N_ROWS * DIM;

    unsigned* wsu = (unsigned*)d_ws;
    float* lossp = (float*)d_ws;                    // [0..256)
    unsigned* hist8 = wsu + 256;                    // [256..4352)
    float* bnp = (float*)(wsu + 4352);              // [4352..4864)
    unsigned short* wfrag = (unsigned short*)(wsu + 4864);  // [4864..37632)

    hipMemsetAsync(d_ws, 0, 17408, stream);         // lossp + hist8
    vq_wprep_k<<<2, 256, 0, stream>>>(Wf, wfrag, bnp);
    vq_score_k<<<N_ROWS / 128, 256, 0, stream>>>(X, wfrag, bnp, out_idx);
    vq_post_k<<<N_ROWS / 16, 256, 0, stream>>>(X, Wf, bnp, out_q, out_idx,
                                               hist8, lossp);
    vq_finalize_k<<<1, 512, 0, stream>>>(hist8, lossp, out_loss, out_perp);
}